// Round 1
// 3999.571 us; speedup vs baseline: 2.1981x; 2.1981x over previous
//
#include <hip/hip_runtime.h>
#include <hip/hip_bf16.h>
#include <math.h>

// Problem constants
#define B_ 8
#define N_ 1025
#define C_ 3200
#define H_ 25
#define D_ 128
#define M_ (B_ * N_)       // 8200 rows
#define C3_ (3 * C_)       // 9600

typedef unsigned short u16;
typedef unsigned int u32;
typedef short bf16x8 __attribute__((ext_vector_type(8)));
typedef float f32x4 __attribute__((ext_vector_type(4)));

__device__ inline void load_lds16(const void* g, void* s) {
    __builtin_amdgcn_global_load_lds(
        (const __attribute__((address_space(1))) void*)g,
        (__attribute__((address_space(3))) void*)s, 16, 0, 0);
}

// Split two fp32 into packed bf16 hi + packed bf16 lo (x0 in low half).
__device__ inline void split_pair(float x0, float x1, u32& hpk, u32& lpk) {
    __hip_bfloat162 h2 = __float22bfloat162_rn(float2{x0, x1});
    union { __hip_bfloat162 b; u32 u; } cv; cv.b = h2;
    u32 h = cv.u;
    float hf0 = __uint_as_float(h << 16);
    float hf1 = __uint_as_float(h & 0xFFFF0000u);
    __hip_bfloat162 l2 = __float22bfloat162_rn(float2{x0 - hf0, x1 - hf1});
    union { __hip_bfloat162 b; u32 u; } cl; cl.b = l2;
    hpk = h; lpk = cl.u;
}

// Split one fp32 into bf16 hi + bf16 lo.
__device__ inline void split1(float x, u16& h, u16& l) {
    union { __hip_bfloat16 b; u16 u; } ch, cl;
    ch.b = __float2bfloat16(x);
    float hf = __uint_as_float(((u32)ch.u) << 16);
    cl.b = __float2bfloat16(x - hf);
    h = ch.u; l = cl.u;
}

// ---------------------------------------------------------------------------
// Fused split-bf16 MFMA GEMM: C[M,N] = A[M,K=3200] @ B[3200,N] + bias.
// (unchanged from previous round; ~900 TF-effective)
// ---------------------------------------------------------------------------
__global__ __launch_bounds__(256) void gemm_split(
    const float* __restrict__ A, const float* __restrict__ Bm,
    const float* __restrict__ bias, float* __restrict__ Cc,
    int M, int N)
{
    __shared__ u16  As_hi[128 * 32];
    __shared__ u16  As_lo[128 * 32];
    __shared__ float Bf[32 * 128];

    const int tid  = threadIdx.x;
    const int lane = tid & 63;
    const int w    = tid >> 6;
    const int wm   = w & 1, wn = w >> 1;
    const int rowBase = blockIdx.y * 128;
    const int colBase = blockIdx.x * 128;
    const int lr = lane & 15, lg = lane >> 4;

    const int ar = tid >> 3;
    const int ak = (tid & 7) * 4;

    f32x4 acc[4][4] = {};

    for (int k0 = 0; k0 < C_; k0 += 32) {
        #pragma unroll
        for (int p = 0; p < 4; ++p) {
            int c = p * 256 + tid;
            const float* g = Bm + (size_t)(k0 + (c >> 5)) * N
                                + colBase + (c & 31) * 4;
            load_lds16(g, &Bf[(p * 256 + w * 64) * 4]);
        }
        #pragma unroll
        for (int p = 0; p < 4; ++p) {
            int r  = p * 32 + ar;
            int gr = rowBase + r; if (gr >= M) gr = M - 1;
            float4 a4 = *(const float4*)(A + (size_t)gr * C_ + k0 + ak);
            u32 h0, h1, l0, l1;
            split_pair(a4.x, a4.y, h0, l0);
            split_pair(a4.z, a4.w, h1, l1);
            *(uint2*)&As_hi[r * 32 + ak] = make_uint2(h0, h1);
            *(uint2*)&As_lo[r * 32 + ak] = make_uint2(l0, l1);
        }
        __syncthreads();

        bf16x8 ah[4], al[4];
        #pragma unroll
        for (int i = 0; i < 4; ++i) {
            ah[i] = *(const bf16x8*)&As_hi[(wm * 64 + i * 16 + lr) * 32 + lg * 8];
            al[i] = *(const bf16x8*)&As_lo[(wm * 64 + i * 16 + lr) * 32 + lg * 8];
        }
        #pragma unroll
        for (int j = 0; j < 4; ++j) {
            const float* bp = &Bf[(lg * 8) * 128 + wn * 64 + j * 16 + lr];
            union { u32 u[4]; bf16x8 v; } BH, BL;
            split_pair(bp[0 * 128], bp[1 * 128], BH.u[0], BL.u[0]);
            split_pair(bp[2 * 128], bp[3 * 128], BH.u[1], BL.u[1]);
            split_pair(bp[4 * 128], bp[5 * 128], BH.u[2], BL.u[2]);
            split_pair(bp[6 * 128], bp[7 * 128], BH.u[3], BL.u[3]);
            #pragma unroll
            for (int i = 0; i < 4; ++i)
                acc[i][j] = __builtin_amdgcn_mfma_f32_16x16x32_bf16(
                    ah[i], BH.v, acc[i][j], 0, 0, 0);
            #pragma unroll
            for (int i = 0; i < 4; ++i)
                acc[i][j] = __builtin_amdgcn_mfma_f32_16x16x32_bf16(
                    al[i], BH.v, acc[i][j], 0, 0, 0);
            #pragma unroll
            for (int i = 0; i < 4; ++i)
                acc[i][j] = __builtin_amdgcn_mfma_f32_16x16x32_bf16(
                    ah[i], BL.v, acc[i][j], 0, 0, 0);
        }
        __syncthreads();
    }

    #pragma unroll
    for (int i = 0; i < 4; ++i) {
        #pragma unroll
        for (int j = 0; j < 4; ++j) {
            int gc = colBase + wn * 64 + j * 16 + lr;
            float bv = bias[gc];
            #pragma unroll
            for (int r = 0; r < 4; ++r) {
                int gr = rowBase + wm * 64 + i * 16 + lg * 4 + r;
                if (gr < M) Cc[(size_t)gr * N + gc] = acc[i][j][r] + bv;
            }
        }
    }
}

// ---------------------------------------------------------------------------
// RMSNorm over full C=3200 for q and k slices. (unchanged)
// ---------------------------------------------------------------------------
__global__ __launch_bounds__(256) void rmsnorm_kernel(
    float* __restrict__ qkv, const float* __restrict__ qw,
    const float* __restrict__ kw)
{
    const int row   = blockIdx.x >> 1;
    const int which = blockIdx.x & 1;
    float* p = qkv + (size_t)row * C3_ + which * C_;
    const float* w = which ? kw : qw;
    const int tid = threadIdx.x;

    float ss = 0.f;
    for (int i = tid; i < C_; i += 256) {
        float v = p[i];
        ss += v * v;
    }
    #pragma unroll
    for (int off = 32; off; off >>= 1) ss += __shfl_down(ss, off);

    __shared__ float wsum[4];
    __shared__ float stot;
    if ((tid & 63) == 0) wsum[tid >> 6] = ss;
    __syncthreads();
    if (tid == 0) stot = wsum[0] + wsum[1] + wsum[2] + wsum[3];
    __syncthreads();

    const float scale = rsqrtf(stot / (float)C_ + 1e-6f);
    for (int i = tid; i < C_; i += 256) p[i] = p[i] * scale * w[i];
}

// ---------------------------------------------------------------------------
// Flash attention via split-bf16 MFMA (3-term, fp32-accurate).
// Block = 64 queries of one (b,h); 4 waves, 16 q-rows each. KV tile = 32.
//
// QK^T: A = Q (rows q, contiguous d), B = K^T -> B-fragment reads K rows
//       with contiguous d (identical addressing to A). K staged in LDS as
//       4 d-chunks of [32 k][32 d] hi/lo (the bank-proven GEMM As layout).
// Softmax: fp32 in-register. C/D layout: k = lane&15, q = (lane>>4)*4+reg,
//       so row-reduce = shfl_xor 1/2/4/8 within 16-lane groups.
// PV:  A = P via small wave-private LDS re-layout; B = V staged TRANSPOSED
//       (Vt[128 d][40] hi/lo) so fragments are contiguous ds_read_b128.
// Next K/V tile is prefetched into registers during compute.
// ---------------------------------------------------------------------------
__global__ __launch_bounds__(256, 2) void flash_mfma(
    const float* __restrict__ qkv, float* __restrict__ attn_out)
{
    __shared__ u16 Kh[4][32][32];    // [d-chunk][k][d-in-chunk] hi
    __shared__ u16 Kl[4][32][32];    // lo
    __shared__ u16 Vth[128][40];     // V^T hi, padded (stride 80B)
    __shared__ u16 Vtl[128][40];     // V^T lo
    __shared__ u16 Ph[4][16][40];    // per-wave P hi, padded for 16B align
    __shared__ u16 Pl[4][16][40];    // per-wave P lo

    const int b   = blockIdx.z;
    const int h   = blockIdx.y;
    const int q0  = blockIdx.x * 64;
    const int tid = threadIdx.x;
    const int lane = tid & 63;
    const int w    = tid >> 6;
    const int lr = lane & 15, lg = lane >> 4;
    const float scale = 0.088388347648318447f;   // D^-0.5

    // ---- Q fragments in registers (hi/lo bf16), scale folded in ----
    bf16x8 qh[4], ql[4];
    {
        int qr = q0 + w * 16 + lr;
        if (qr >= N_) qr = N_ - 1;
        const float* qp = qkv + (size_t)(b * N_ + qr) * C3_ + h * D_;
        #pragma unroll
        for (int c = 0; c < 4; ++c) {
            float4 x0 = *(const float4*)(qp + c * 32 + lg * 8);
            float4 x1 = *(const float4*)(qp + c * 32 + lg * 8 + 4);
            union { u32 u[4]; bf16x8 v; } Hq, Lq;
            split_pair(x0.x * scale, x0.y * scale, Hq.u[0], Lq.u[0]);
            split_pair(x0.z * scale, x0.w * scale, Hq.u[1], Lq.u[1]);
            split_pair(x1.x * scale, x1.y * scale, Hq.u[2], Lq.u[2]);
            split_pair(x1.z * scale, x1.w * scale, Hq.u[3], Lq.u[3]);
            qh[c] = Hq.v; ql[c] = Lq.v;
        }
    }

    // K/V row bases for this (b,h)
    const float* Kbase = qkv + (size_t)b * N_ * C3_ + C_ + h * D_;
    const float* Vbase = qkv + (size_t)b * N_ * C3_ + 2 * C_ + h * D_;

    // staging thread mappings
    const int skr = tid >> 3;          // K: k row 0..31
    const int skd = (tid & 7) * 16;    // K: d0 (16 floats per thread)
    const int svk = (tid & 15) * 2;    // V: k pair base (even)
    const int svd = (tid >> 4) * 4;    // V: d base 0..60 (+64 second half)

    float4 kg[4], vg[2][2];            // prefetch registers

    auto stage_load = [&](int kt) {
        int kk = kt * 32 + skr;
        if (kk < N_) {
            const float* p = Kbase + (size_t)kk * C3_ + skd;
            kg[0] = *(const float4*)(p + 0);
            kg[1] = *(const float4*)(p + 4);
            kg[2] = *(const float4*)(p + 8);
            kg[3] = *(const float4*)(p + 12);
        } else {
            kg[0] = kg[1] = kg[2] = kg[3] = make_float4(0.f, 0.f, 0.f, 0.f);
        }
        #pragma unroll
        for (int r = 0; r < 2; ++r) {
            int vk = kt * 32 + svk + r;
            if (vk < N_) {
                const float* p = Vbase + (size_t)vk * C3_ + svd;
                vg[0][r] = *(const float4*)(p);
                vg[1][r] = *(const float4*)(p + 64);
            } else {
                vg[0][r] = make_float4(0.f, 0.f, 0.f, 0.f);
                vg[1][r] = make_float4(0.f, 0.f, 0.f, 0.f);
            }
        }
    };

    auto stage_store = [&]() {
        // K -> d-chunked hi/lo tiles
        #pragma unroll
        for (int i = 0; i < 4; ++i) {
            int d = skd + i * 4;
            int c = d >> 5, dd = d & 31;
            u32 h0, l0, h1, l1;
            split_pair(kg[i].x, kg[i].y, h0, l0);
            split_pair(kg[i].z, kg[i].w, h1, l1);
            *(uint2*)&Kh[c][skr][dd] = make_uint2(h0, h1);
            *(uint2*)&Kl[c][skr][dd] = make_uint2(l0, l1);
        }
        // V -> transposed hi/lo tiles (pack k-pair into one dword)
        #pragma unroll
        for (int half = 0; half < 2; ++half) {
            float a0[4] = { vg[half][0].x, vg[half][0].y, vg[half][0].z, vg[half][0].w };
            float a1[4] = { vg[half][1].x, vg[half][1].y, vg[half][1].z, vg[half][1].w };
            #pragma unroll
            for (int i = 0; i < 4; ++i) {
                int d = svd + half * 64 + i;
                u32 hp, lp;
                split_pair(a0[i], a1[i], hp, lp);
                *(u32*)&Vth[d][svk] = hp;
                *(u32*)&Vtl[d][svk] = lp;
            }
        }
    };

    f32x4 oacc[8] = {};
    float m[4]    = { -INFINITY, -INFINITY, -INFINITY, -INFINITY };
    float lsum[4] = { 0.f, 0.f, 0.f, 0.f };

    const int nkt = (N_ + 31) / 32;
    stage_load(0);
    for (int kt = 0; kt < nkt; ++kt) {
        __syncthreads();            // previous compute done with LDS
        stage_store();
        __syncthreads();            // tile ready
        if (kt + 1 < nkt) stage_load(kt + 1);   // hide under compute

        // ---- QK^T: S[16 q][32 k], 3-term split ----
        f32x4 s0 = {}, s1 = {};
        #pragma unroll
        for (int c = 0; c < 4; ++c) {
            bf16x8 kh0 = *(const bf16x8*)&Kh[c][lr][lg * 8];
            bf16x8 kl0 = *(const bf16x8*)&Kl[c][lr][lg * 8];
            bf16x8 kh1 = *(const bf16x8*)&Kh[c][16 + lr][lg * 8];
            bf16x8 kl1 = *(const bf16x8*)&Kl[c][16 + lr][lg * 8];
            s0 = __builtin_amdgcn_mfma_f32_16x16x32_bf16(qh[c], kh0, s0, 0, 0, 0);
            s0 = __builtin_amdgcn_mfma_f32_16x16x32_bf16(ql[c], kh0, s0, 0, 0, 0);
            s0 = __builtin_amdgcn_mfma_f32_16x16x32_bf16(qh[c], kl0, s0, 0, 0, 0);
            s1 = __builtin_amdgcn_mfma_f32_16x16x32_bf16(qh[c], kh1, s1, 0, 0, 0);
            s1 = __builtin_amdgcn_mfma_f32_16x16x32_bf16(ql[c], kh1, s1, 0, 0, 0);
            s1 = __builtin_amdgcn_mfma_f32_16x16x32_bf16(qh[c], kl1, s1, 0, 0, 0);
        }

        // mask invalid k columns (this lane's k = kt*32 + {lr, 16+lr})
        const int kb = kt * 32;
        const bool v0 = (kb + lr) < N_;
        const bool v1 = (kb + 16 + lr) < N_;
        #pragma unroll
        for (int r = 0; r < 4; ++r) {
            if (!v0) s0[r] = -INFINITY;
            if (!v1) s1[r] = -INFINITY;
        }

        // ---- online softmax (fp32, in-register) ----
        #pragma unroll
        for (int r = 0; r < 4; ++r) {
            float mt = fmaxf(s0[r], s1[r]);
            mt = fmaxf(mt, __shfl_xor(mt, 1));
            mt = fmaxf(mt, __shfl_xor(mt, 2));
            mt = fmaxf(mt, __shfl_xor(mt, 4));
            mt = fmaxf(mt, __shfl_xor(mt, 8));
            float mn = fmaxf(m[r], mt);
            float al = __expf(m[r] - mn);
            m[r] = mn;
            float p0 = __expf(s0[r] - mn);
            float p1 = __expf(s1[r] - mn);
            float ls = p0 + p1;
            ls += __shfl_xor(ls, 1);
            ls += __shfl_xor(ls, 2);
            ls += __shfl_xor(ls, 4);
            ls += __shfl_xor(ls, 8);
            lsum[r] = lsum[r] * al + ls;
            #pragma unroll
            for (int dt = 0; dt < 8; ++dt) oacc[dt][r] *= al;

            // P -> wave-private LDS (row = q-local, col = k)
            u16 hh, ll;
            split1(p0, hh, ll);
            Ph[w][lg * 4 + r][lr] = hh;
            Pl[w][lg * 4 + r][lr] = ll;
            split1(p1, hh, ll);
            Ph[w][lg * 4 + r][16 + lr] = hh;
            Pl[w][lg * 4 + r][16 + lr] = ll;
        }

        // ---- PV: O[16 q][128 d] += P[16][32] @ V[32][128], 3-term ----
        bf16x8 pah = *(const bf16x8*)&Ph[w][lr][lg * 8];
        bf16x8 pal = *(const bf16x8*)&Pl[w][lr][lg * 8];
        #pragma unroll
        for (int dt = 0; dt < 8; ++dt) {
            bf16x8 vh = *(const bf16x8*)&Vth[dt * 16 + lr][lg * 8];
            bf16x8 vl = *(const bf16x8*)&Vtl[dt * 16 + lr][lg * 8];
            oacc[dt] = __builtin_amdgcn_mfma_f32_16x16x32_bf16(pah, vh, oacc[dt], 0, 0, 0);
            oacc[dt] = __builtin_amdgcn_mfma_f32_16x16x32_bf16(pal, vh, oacc[dt], 0, 0, 0);
            oacc[dt] = __builtin_amdgcn_mfma_f32_16x16x32_bf16(pah, vl, oacc[dt], 0, 0, 0);
        }
    }

    // ---- epilogue: O layout d = dt*16 + (lane&15), q = (lane>>4)*4 + r ----
    #pragma unroll
    for (int r = 0; r < 4; ++r) {
        int q = q0 + w * 16 + lg * 4 + r;
        if (q < N_) {
            float inv = 1.f / lsum[r];
            float* op = attn_out + (size_t)(b * N_ + q) * C_ + h * D_ + lr;
            #pragma unroll
            for (int dt = 0; dt < 8; ++dt) op[dt * 16] = oacc[dt][r] * inv;
        }
    }
}

// ---------------------------------------------------------------------------
extern "C" void kernel_launch(void* const* d_in, const int* in_sizes, int n_in,
                              void* d_out, int out_size, void* d_ws, size_t ws_size,
                              hipStream_t stream)
{
    const float* x        = (const float*)d_in[0];
    const float* qkv_w    = (const float*)d_in[1];
    const float* qkv_b    = (const float*)d_in[2];
    const float* q_norm_w = (const float*)d_in[3];
    const float* k_norm_w = (const float*)d_in[4];
    const float* proj_w   = (const float*)d_in[5];
    const float* proj_b   = (const float*)d_in[6];
    float* out = (float*)d_out;

    // workspace: qkv fp32 (315 MB) + attn_out fp32 (105 MB) = 420 MB
    float* qkv      = (float*)d_ws;
    float* attn_out = qkv + (size_t)M_ * C3_;

    dim3 blk(256);

    // 1) QKV GEMM (fused split-bf16 MFMA): [8200,3200] @ [3200,9600] + bias
    gemm_split<<<dim3(C3_ / 128, (M_ + 127) / 128), blk, 0, stream>>>(
        x, qkv_w, qkv_b, qkv, M_, C3_);

    // 2) RMSNorm on q and k slices
    rmsnorm_kernel<<<dim3(M_ * 2), blk, 0, stream>>>(qkv, q_norm_w, k_norm_w);

    // 3) Flash attention (split-bf16 MFMA)
    flash_mfma<<<dim3((N_ + 63) / 64, H_, B_), blk, 0, stream>>>(qkv, attn_out);

    // 4) Output projection (fused split-bf16 MFMA): [8200,3200] @ [3200,3200] + bias
    gemm_split<<<dim3(C_ / 128, (M_ + 127) / 128), blk, 0, stream>>>(
        attn_out, proj_w, proj_b, out, M_, C_);
}

// Round 2
// 3998.550 us; speedup vs baseline: 2.1987x; 1.0003x over previous
//
#include <hip/hip_runtime.h>
#include <hip/hip_bf16.h>
#include <math.h>

// Problem constants
#define B_ 8
#define N_ 1025
#define C_ 3200
#define H_ 25
#define D_ 128
#define M_ (B_ * N_)       // 8200 rows
#define C3_ (3 * C_)       // 9600

typedef unsigned short u16;
typedef unsigned int u32;
typedef short bf16x8 __attribute__((ext_vector_type(8)));
typedef float f32x4 __attribute__((ext_vector_type(4)));

__device__ inline void load_lds16(const void* g, void* s) {
    __builtin_amdgcn_global_load_lds(
        (const __attribute__((address_space(1))) void*)g,
        (__attribute__((address_space(3))) void*)s, 16, 0, 0);
}

// Split two fp32 into packed bf16 hi + packed bf16 lo (x0 in low half).
__device__ inline void split_pair(float x0, float x1, u32& hpk, u32& lpk) {
    __hip_bfloat162 h2 = __float22bfloat162_rn(float2{x0, x1});
    union { __hip_bfloat162 b; u32 u; } cv; cv.b = h2;
    u32 h = cv.u;
    float hf0 = __uint_as_float(h << 16);
    float hf1 = __uint_as_float(h & 0xFFFF0000u);
    __hip_bfloat162 l2 = __float22bfloat162_rn(float2{x0 - hf0, x1 - hf1});
    union { __hip_bfloat162 b; u32 u; } cl; cl.b = l2;
    hpk = h; lpk = cl.u;
}

// Split one fp32 into bf16 hi + bf16 lo.
__device__ inline void split1(float x, u16& h, u16& l) {
    union { __hip_bfloat16 b; u16 u; } ch, cl;
    ch.b = __float2bfloat16(x);
    float hf = __uint_as_float(((u32)ch.u) << 16);
    cl.b = __float2bfloat16(x - hf);
    h = ch.u; l = cl.u;
}

// ---------------------------------------------------------------------------
// Elementwise fp32 -> bf16 hi/lo split (no transpose). 4 floats per thread.
// ---------------------------------------------------------------------------
__global__ __launch_bounds__(256) void convert_split(
    const float4* __restrict__ in, uint2* __restrict__ hi,
    uint2* __restrict__ lo, int n4)
{
    int i = blockIdx.x * 256 + threadIdx.x;
    if (i < n4) {
        float4 v = in[i];
        u32 h0, l0, h1, l1;
        split_pair(v.x, v.y, h0, l0);
        split_pair(v.z, v.w, h1, l1);
        hi[i] = make_uint2(h0, h1);
        lo[i] = make_uint2(l0, l1);
    }
}

// ---------------------------------------------------------------------------
// Transpose + split: in fp32 [K][Nn] row-major -> out bf16 hi/lo [Nn][K]
// (k-contiguous). 32x32 tiles through LDS.
// ---------------------------------------------------------------------------
__global__ __launch_bounds__(256) void convert_tsplit(
    const float* __restrict__ in, u16* __restrict__ hi, u16* __restrict__ lo,
    int K, int Nn)
{
    __shared__ float T[32][33];
    const int tid = threadIdx.x;
    const int nb = blockIdx.x * 32, kb = blockIdx.y * 32;
    #pragma unroll
    for (int p = 0; p < 4; ++p) {
        int k = p * 8 + (tid >> 5), n = tid & 31;
        T[k][n] = in[(size_t)(kb + k) * Nn + nb + n];
    }
    __syncthreads();
    const int nn = tid >> 3, k0 = (tid & 7) * 4;
    u32 h0, l0, h1, l1;
    split_pair(T[k0][nn], T[k0 + 1][nn], h0, l0);
    split_pair(T[k0 + 2][nn], T[k0 + 3][nn], h1, l1);
    size_t o = (size_t)(nb + nn) * K + kb + k0;
    *(uint2*)&hi[o] = make_uint2(h0, h1);
    *(uint2*)&lo[o] = make_uint2(l0, l1);
}

// ---------------------------------------------------------------------------
// All-bf16 split GEMM: C[M,N] = A[M,K] @ B[K,N] + bias, 3-term split.
// A given as hi/lo bf16 [M][K]; B given as hi/lo bf16 TRANSPOSED [N][K].
// 128x128 tile, BK=32, 4 waves (2x2), 16x16x32 bf16 MFMA, pure
// global_load_lds staging (no VALU conversion in the loop).
// LDS layout [kchunk 4][row 128][8 k] -> fragment = contiguous ds_read_b128,
// stride 16B within 16-lane group => 2 lanes/bank (conflict-free).
// Bijective XCD swizzle (m204) for L2/L3 locality.
// ---------------------------------------------------------------------------
__global__ __launch_bounds__(256) void gemm_bf16split(
    const u16* __restrict__ Ah, const u16* __restrict__ Al,
    const u16* __restrict__ Bh, const u16* __restrict__ Bl,
    const float* __restrict__ bias, float* __restrict__ Cc,
    int M, int N)
{
    __shared__ u16 As_h[4][128][8];
    __shared__ u16 As_l[4][128][8];
    __shared__ u16 Bs_h[4][128][8];
    __shared__ u16 Bs_l[4][128][8];

    const int tid  = threadIdx.x;
    const int lane = tid & 63;
    const int w    = tid >> 6;
    const int wm   = w & 1, wn = w >> 1;
    const int lr = lane & 15, lg = lane >> 4;

    // bijective XCD-aware remap of the linear block id (8 XCDs)
    const int gX   = gridDim.x;
    const int nwg  = gX * gridDim.y;
    const int orig = blockIdx.y * gX + blockIdx.x;
    const int q8 = nwg >> 3, r8 = nwg & 7;
    const int xcd = orig & 7, oi = orig >> 3;
    const int wg = (xcd < r8 ? xcd * (q8 + 1)
                             : r8 * (q8 + 1) + (xcd - r8) * q8) + oi;
    const int rowBase = (wg / gX) * 128;
    const int colBase = (wg % gX) * 128;

    f32x4 acc[4][4] = {};

    for (int k0 = 0; k0 < C_; k0 += 32) {
        // ---- stage 4 tiles (8KB each) via 16B global->LDS DMA ----
        #pragma unroll
        for (int p = 0; p < 2; ++p) {
            int c   = p * 256 + tid;            // chunk id 0..511
            int row = c & 127, kc = c >> 7;
            int ldsOff = (p * 256 + w * 64) * 8;     // u16 units, wave-uniform
            int ar = rowBase + row; if (ar >= M) ar = M - 1;
            size_t aoff = (size_t)ar * C_ + k0 + kc * 8;
            size_t boff = (size_t)(colBase + row) * C_ + k0 + kc * 8;
            load_lds16(Ah + aoff, (u16*)As_h + ldsOff);
            load_lds16(Al + aoff, (u16*)As_l + ldsOff);
            load_lds16(Bh + boff, (u16*)Bs_h + ldsOff);
            load_lds16(Bl + boff, (u16*)Bs_l + ldsOff);
        }
        __syncthreads();

        // ---- fragments: contiguous b128 reads ----
        bf16x8 ah[4], al[4], bh[4], bl[4];
        #pragma unroll
        for (int i = 0; i < 4; ++i) {
            ah[i] = *(const bf16x8*)&As_h[lg][wm * 64 + i * 16 + lr][0];
            al[i] = *(const bf16x8*)&As_l[lg][wm * 64 + i * 16 + lr][0];
            bh[i] = *(const bf16x8*)&Bs_h[lg][wn * 64 + i * 16 + lr][0];
            bl[i] = *(const bf16x8*)&Bs_l[lg][wn * 64 + i * 16 + lr][0];
        }

        // ---- 48 MFMA: Ah*Bh + Al*Bh + Ah*Bl ----
        #pragma unroll
        for (int j = 0; j < 4; ++j)
            #pragma unroll
            for (int i = 0; i < 4; ++i)
                acc[i][j] = __builtin_amdgcn_mfma_f32_16x16x32_bf16(
                    ah[i], bh[j], acc[i][j], 0, 0, 0);
        #pragma unroll
        for (int j = 0; j < 4; ++j)
            #pragma unroll
            for (int i = 0; i < 4; ++i)
                acc[i][j] = __builtin_amdgcn_mfma_f32_16x16x32_bf16(
                    al[i], bh[j], acc[i][j], 0, 0, 0);
        #pragma unroll
        for (int j = 0; j < 4; ++j)
            #pragma unroll
            for (int i = 0; i < 4; ++i)
                acc[i][j] = __builtin_amdgcn_mfma_f32_16x16x32_bf16(
                    ah[i], bl[j], acc[i][j], 0, 0, 0);
        __syncthreads();
    }

    // ---- epilogue: C/D layout col=lane&15, row=(lane>>4)*4+reg ----
    #pragma unroll
    for (int i = 0; i < 4; ++i) {
        #pragma unroll
        for (int j = 0; j < 4; ++j) {
            int gc = colBase + wn * 64 + j * 16 + lr;
            float bv = bias[gc];
            #pragma unroll
            for (int r = 0; r < 4; ++r) {
                int gr = rowBase + wm * 64 + i * 16 + lg * 4 + r;
                if (gr < M) Cc[(size_t)gr * N + gc] = acc[i][j][r] + bv;
            }
        }
    }
}

// ---------------------------------------------------------------------------
// Fallback fused split-bf16 GEMM (fp32 inputs, in-loop conversion) — used
// only if the workspace is too small for the pre-converted arrays.
// ---------------------------------------------------------------------------
__global__ __launch_bounds__(256) void gemm_split(
    const float* __restrict__ A, const float* __restrict__ Bm,
    const float* __restrict__ bias, float* __restrict__ Cc,
    int M, int N)
{
    __shared__ u16  As_hi[128 * 32];
    __shared__ u16  As_lo[128 * 32];
    __shared__ float Bf[32 * 128];

    const int tid  = threadIdx.x;
    const int lane = tid & 63;
    const int w    = tid >> 6;
    const int wm   = w & 1, wn = w >> 1;
    const int rowBase = blockIdx.y * 128;
    const int colBase = blockIdx.x * 128;
    const int lr = lane & 15, lg = lane >> 4;

    const int ar = tid >> 3;
    const int ak = (tid & 7) * 4;

    f32x4 acc[4][4] = {};

    for (int k0 = 0; k0 < C_; k0 += 32) {
        #pragma unroll
        for (int p = 0; p < 4; ++p) {
            int c = p * 256 + tid;
            const float* g = Bm + (size_t)(k0 + (c >> 5)) * N
                                + colBase + (c & 31) * 4;
            load_lds16(g, &Bf[(p * 256 + w * 64) * 4]);
        }
        #pragma unroll
        for (int p = 0; p < 4; ++p) {
            int r  = p * 32 + ar;
            int gr = rowBase + r; if (gr >= M) gr = M - 1;
            float4 a4 = *(const float4*)(A + (size_t)gr * C_ + k0 + ak);
            u32 h0, h1, l0, l1;
            split_pair(a4.x, a4.y, h0, l0);
            split_pair(a4.z, a4.w, h1, l1);
            *(uint2*)&As_hi[r * 32 + ak] = make_uint2(h0, h1);
            *(uint2*)&As_lo[r * 32 + ak] = make_uint2(l0, l1);
        }
        __syncthreads();

        bf16x8 ah[4], al[4];
        #pragma unroll
        for (int i = 0; i < 4; ++i) {
            ah[i] = *(const bf16x8*)&As_hi[(wm * 64 + i * 16 + lr) * 32 + lg * 8];
            al[i] = *(const bf16x8*)&As_lo[(wm * 64 + i * 16 + lr) * 32 + lg * 8];
        }
        #pragma unroll
        for (int j = 0; j < 4; ++j) {
            const float* bp = &Bf[(lg * 8) * 128 + wn * 64 + j * 16 + lr];
            union { u32 u[4]; bf16x8 v; } BH, BL;
            split_pair(bp[0 * 128], bp[1 * 128], BH.u[0], BL.u[0]);
            split_pair(bp[2 * 128], bp[3 * 128], BH.u[1], BL.u[1]);
            split_pair(bp[4 * 128], bp[5 * 128], BH.u[2], BL.u[2]);
            split_pair(bp[6 * 128], bp[7 * 128], BH.u[3], BL.u[3]);
            #pragma unroll
            for (int i = 0; i < 4; ++i)
                acc[i][j] = __builtin_amdgcn_mfma_f32_16x16x32_bf16(
                    ah[i], BH.v, acc[i][j], 0, 0, 0);
            #pragma unroll
            for (int i = 0; i < 4; ++i)
                acc[i][j] = __builtin_amdgcn_mfma_f32_16x16x32_bf16(
                    al[i], BH.v, acc[i][j], 0, 0, 0);
            #pragma unroll
            for (int i = 0; i < 4; ++i)
                acc[i][j] = __builtin_amdgcn_mfma_f32_16x16x32_bf16(
                    ah[i], BL.v, acc[i][j], 0, 0, 0);
        }
        __syncthreads();
    }

    #pragma unroll
    for (int i = 0; i < 4; ++i) {
        #pragma unroll
        for (int j = 0; j < 4; ++j) {
            int gc = colBase + wn * 64 + j * 16 + lr;
            float bv = bias[gc];
            #pragma unroll
            for (int r = 0; r < 4; ++r) {
                int gr = rowBase + wm * 64 + i * 16 + lg * 4 + r;
                if (gr < M) Cc[(size_t)gr * N + gc] = acc[i][j][r] + bv;
            }
        }
    }
}

// ---------------------------------------------------------------------------
// RMSNorm over full C=3200 for q and k slices (float4 vectorized).
// ---------------------------------------------------------------------------
__global__ __launch_bounds__(256) void rmsnorm_kernel(
    float* __restrict__ qkv, const float* __restrict__ qw,
    const float* __restrict__ kw)
{
    const int row   = blockIdx.x >> 1;
    const int which = blockIdx.x & 1;
    float* p = qkv + (size_t)row * C3_ + which * C_;
    const float* w = which ? kw : qw;
    const int tid = threadIdx.x;

    float ss = 0.f;
    for (int i = tid; i < C_ / 4; i += 256) {
        float4 v = ((const float4*)p)[i];
        ss += v.x * v.x + v.y * v.y + v.z * v.z + v.w * v.w;
    }
    #pragma unroll
    for (int off = 32; off; off >>= 1) ss += __shfl_down(ss, off);

    __shared__ float wsum[4];
    __shared__ float stot;
    if ((tid & 63) == 0) wsum[tid >> 6] = ss;
    __syncthreads();
    if (tid == 0) stot = wsum[0] + wsum[1] + wsum[2] + wsum[3];
    __syncthreads();

    const float scale = rsqrtf(stot / (float)C_ + 1e-6f);
    for (int i = tid; i < C_ / 4; i += 256) {
        float4 v  = ((const float4*)p)[i];
        float4 wv = ((const float4*)w)[i];
        v.x *= scale * wv.x; v.y *= scale * wv.y;
        v.z *= scale * wv.z; v.w *= scale * wv.w;
        ((float4*)p)[i] = v;
    }
}

// ---------------------------------------------------------------------------
// Flash attention via split-bf16 MFMA (3-term, fp32-accurate). (unchanged)
// ---------------------------------------------------------------------------
__global__ __launch_bounds__(256, 2) void flash_mfma(
    const float* __restrict__ qkv, float* __restrict__ attn_out)
{
    __shared__ u16 Kh[4][32][32];
    __shared__ u16 Kl[4][32][32];
    __shared__ u16 Vth[128][40];
    __shared__ u16 Vtl[128][40];
    __shared__ u16 Ph[4][16][40];
    __shared__ u16 Pl[4][16][40];

    const int b   = blockIdx.z;
    const int h   = blockIdx.y;
    const int q0  = blockIdx.x * 64;
    const int tid = threadIdx.x;
    const int lane = tid & 63;
    const int w    = tid >> 6;
    const int lr = lane & 15, lg = lane >> 4;
    const float scale = 0.088388347648318447f;

    bf16x8 qh[4], ql[4];
    {
        int qr = q0 + w * 16 + lr;
        if (qr >= N_) qr = N_ - 1;
        const float* qp = qkv + (size_t)(b * N_ + qr) * C3_ + h * D_;
        #pragma unroll
        for (int c = 0; c < 4; ++c) {
            float4 x0 = *(const float4*)(qp + c * 32 + lg * 8);
            float4 x1 = *(const float4*)(qp + c * 32 + lg * 8 + 4);
            union { u32 u[4]; bf16x8 v; } Hq, Lq;
            split_pair(x0.x * scale, x0.y * scale, Hq.u[0], Lq.u[0]);
            split_pair(x0.z * scale, x0.w * scale, Hq.u[1], Lq.u[1]);
            split_pair(x1.x * scale, x1.y * scale, Hq.u[2], Lq.u[2]);
            split_pair(x1.z * scale, x1.w * scale, Hq.u[3], Lq.u[3]);
            qh[c] = Hq.v; ql[c] = Lq.v;
        }
    }

    const float* Kbase = qkv + (size_t)b * N_ * C3_ + C_ + h * D_;
    const float* Vbase = qkv + (size_t)b * N_ * C3_ + 2 * C_ + h * D_;

    const int skr = tid >> 3;
    const int skd = (tid & 7) * 16;
    const int svk = (tid & 15) * 2;
    const int svd = (tid >> 4) * 4;

    float4 kg[4], vg[2][2];

    auto stage_load = [&](int kt) {
        int kk = kt * 32 + skr;
        if (kk < N_) {
            const float* p = Kbase + (size_t)kk * C3_ + skd;
            kg[0] = *(const float4*)(p + 0);
            kg[1] = *(const float4*)(p + 4);
            kg[2] = *(const float4*)(p + 8);
            kg[3] = *(const float4*)(p + 12);
        } else {
            kg[0] = kg[1] = kg[2] = kg[3] = make_float4(0.f, 0.f, 0.f, 0.f);
        }
        #pragma unroll
        for (int r = 0; r < 2; ++r) {
            int vk = kt * 32 + svk + r;
            if (vk < N_) {
                const float* p = Vbase + (size_t)vk * C3_ + svd;
                vg[0][r] = *(const float4*)(p);
                vg[1][r] = *(const float4*)(p + 64);
            } else {
                vg[0][r] = make_float4(0.f, 0.f, 0.f, 0.f);
                vg[1][r] = make_float4(0.f, 0.f, 0.f, 0.f);
            }
        }
    };

    auto stage_store = [&]() {
        #pragma unroll
        for (int i = 0; i < 4; ++i) {
            int d = skd + i * 4;
            int c = d >> 5, dd = d & 31;
            u32 h0, l0, h1, l1;
            split_pair(kg[i].x, kg[i].y, h0, l0);
            split_pair(kg[i].z, kg[i].w, h1, l1);
            *(uint2*)&Kh[c][skr][dd] = make_uint2(h0, h1);
            *(uint2*)&Kl[c][skr][dd] = make_uint2(l0, l1);
        }
        #pragma unroll
        for (int half = 0; half < 2; ++half) {
            float a0[4] = { vg[half][0].x, vg[half][0].y, vg[half][0].z, vg[half][0].w };
            float a1[4] = { vg[half][1].x, vg[half][1].y, vg[half][1].z, vg[half][1].w };
            #pragma unroll
            for (int i = 0; i < 4; ++i) {
                int d = svd + half * 64 + i;
                u32 hp, lp;
                split_pair(a0[i], a1[i], hp, lp);
                *(u32*)&Vth[d][svk] = hp;
                *(u32*)&Vtl[d][svk] = lp;
            }
        }
    };

    f32x4 oacc[8] = {};
    float m[4]    = { -INFINITY, -INFINITY, -INFINITY, -INFINITY };
    float lsum[4] = { 0.f, 0.f, 0.f, 0.f };

    const int nkt = (N_ + 31) / 32;
    stage_load(0);
    for (int kt = 0; kt < nkt; ++kt) {
        __syncthreads();
        stage_store();
        __syncthreads();
        if (kt + 1 < nkt) stage_load(kt + 1);

        f32x4 s0 = {}, s1 = {};
        #pragma unroll
        for (int c = 0; c < 4; ++c) {
            bf16x8 kh0 = *(const bf16x8*)&Kh[c][lr][lg * 8];
            bf16x8 kl0 = *(const bf16x8*)&Kl[c][lr][lg * 8];
            bf16x8 kh1 = *(const bf16x8*)&Kh[c][16 + lr][lg * 8];
            bf16x8 kl1 = *(const bf16x8*)&Kl[c][16 + lr][lg * 8];
            s0 = __builtin_amdgcn_mfma_f32_16x16x32_bf16(qh[c], kh0, s0, 0, 0, 0);
            s0 = __builtin_amdgcn_mfma_f32_16x16x32_bf16(ql[c], kh0, s0, 0, 0, 0);
            s0 = __builtin_amdgcn_mfma_f32_16x16x32_bf16(qh[c], kl0, s0, 0, 0, 0);
            s1 = __builtin_amdgcn_mfma_f32_16x16x32_bf16(qh[c], kh1, s1, 0, 0, 0);
            s1 = __builtin_amdgcn_mfma_f32_16x16x32_bf16(ql[c], kh1, s1, 0, 0, 0);
            s1 = __builtin_amdgcn_mfma_f32_16x16x32_bf16(qh[c], kl1, s1, 0, 0, 0);
        }

        const int kb = kt * 32;
        const bool v0 = (kb + lr) < N_;
        const bool v1 = (kb + 16 + lr) < N_;
        #pragma unroll
        for (int r = 0; r < 4; ++r) {
            if (!v0) s0[r] = -INFINITY;
            if (!v1) s1[r] = -INFINITY;
        }

        #pragma unroll
        for (int r = 0; r < 4; ++r) {
            float mt = fmaxf(s0[r], s1[r]);
            mt = fmaxf(mt, __shfl_xor(mt, 1));
            mt = fmaxf(mt, __shfl_xor(mt, 2));
            mt = fmaxf(mt, __shfl_xor(mt, 4));
            mt = fmaxf(mt, __shfl_xor(mt, 8));
            float mn = fmaxf(m[r], mt);
            float al = __expf(m[r] - mn);
            m[r] = mn;
            float p0 = __expf(s0[r] - mn);
            float p1 = __expf(s1[r] - mn);
            float ls = p0 + p1;
            ls += __shfl_xor(ls, 1);
            ls += __shfl_xor(ls, 2);
            ls += __shfl_xor(ls, 4);
            ls += __shfl_xor(ls, 8);
            lsum[r] = lsum[r] * al + ls;
            #pragma unroll
            for (int dt = 0; dt < 8; ++dt) oacc[dt][r] *= al;

            u16 hh, ll;
            split1(p0, hh, ll);
            Ph[w][lg * 4 + r][lr] = hh;
            Pl[w][lg * 4 + r][lr] = ll;
            split1(p1, hh, ll);
            Ph[w][lg * 4 + r][16 + lr] = hh;
            Pl[w][lg * 4 + r][16 + lr] = ll;
        }

        bf16x8 pah = *(const bf16x8*)&Ph[w][lr][lg * 8];
        bf16x8 pal = *(const bf16x8*)&Pl[w][lr][lg * 8];
        #pragma unroll
        for (int dt = 0; dt < 8; ++dt) {
            bf16x8 vh = *(const bf16x8*)&Vth[dt * 16 + lr][lg * 8];
            bf16x8 vl = *(const bf16x8*)&Vtl[dt * 16 + lr][lg * 8];
            oacc[dt] = __builtin_amdgcn_mfma_f32_16x16x32_bf16(pah, vh, oacc[dt], 0, 0, 0);
            oacc[dt] = __builtin_amdgcn_mfma_f32_16x16x32_bf16(pal, vh, oacc[dt], 0, 0, 0);
            oacc[dt] = __builtin_amdgcn_mfma_f32_16x16x32_bf16(pah, vl, oacc[dt], 0, 0, 0);
        }
    }

    #pragma unroll
    for (int r = 0; r < 4; ++r) {
        int q = q0 + w * 16 + lg * 4 + r;
        if (q < N_) {
            float inv = 1.f / lsum[r];
            float* op = attn_out + (size_t)(b * N_ + q) * C_ + h * D_ + lr;
            #pragma unroll
            for (int dt = 0; dt < 8; ++dt) op[dt * 16] = oacc[dt][r] * inv;
        }
    }
}

// ---------------------------------------------------------------------------
extern "C" void kernel_launch(void* const* d_in, const int* in_sizes, int n_in,
                              void* d_out, int out_size, void* d_ws, size_t ws_size,
                              hipStream_t stream)
{
    const float* x        = (const float*)d_in[0];
    const float* qkv_w    = (const float*)d_in[1];
    const float* qkv_b    = (const float*)d_in[2];
    const float* q_norm_w = (const float*)d_in[3];
    const float* k_norm_w = (const float*)d_in[4];
    const float* proj_w   = (const float*)d_in[5];
    const float* proj_b   = (const float*)d_in[6];
    float* out = (float*)d_out;

    const size_t fQ = (size_t)M_ * C3_;    // qkv floats
    const size_t fA = (size_t)M_ * C_;     // attn_out floats (= split elems)
    const size_t uW = (size_t)C3_ * C_;    // weight split elems (max)

    float* qkv      = (float*)d_ws;
    float* attn_out = qkv + fQ;

    const size_t need = (fQ + fA) * 4 + fA * 2 * 2 + uW * 2 * 2;

    dim3 blk(256);

    if (ws_size >= need) {
        u16* xh = (u16*)(attn_out + fA);
        u16* xl = xh + fA;
        u16* wh = xl + fA;
        u16* wl = wh + uW;

        const int n4 = (int)(fA / 4);

        // 1) pre-split x and qkv_w^T
        convert_split<<<dim3((n4 + 255) / 256), blk, 0, stream>>>(
            (const float4*)x, (uint2*)xh, (uint2*)xl, n4);
        convert_tsplit<<<dim3(C3_ / 32, C_ / 32), blk, 0, stream>>>(
            qkv_w, wh, wl, C_, C3_);

        // 2) QKV GEMM: [8200,3200] @ [3200,9600] + bias
        gemm_bf16split<<<dim3(C3_ / 128, (M_ + 127) / 128), blk, 0, stream>>>(
            xh, xl, wh, wl, qkv_b, qkv, M_, C3_);

        // 3) RMSNorm on q and k slices
        rmsnorm_kernel<<<dim3(M_ * 2), blk, 0, stream>>>(qkv, q_norm_w, k_norm_w);

        // 4) Flash attention
        flash_mfma<<<dim3((N_ + 63) / 64, H_, B_), blk, 0, stream>>>(qkv, attn_out);

        // 5) pre-split attn_out (reuse x buffers) and proj_w^T (reuse w buffers)
        convert_split<<<dim3((n4 + 255) / 256), blk, 0, stream>>>(
            (const float4*)attn_out, (uint2*)xh, (uint2*)xl, n4);
        convert_tsplit<<<dim3(C_ / 32, C_ / 32), blk, 0, stream>>>(
            proj_w, wh, wl, C_, C_);

        // 6) Output projection: [8200,3200] @ [3200,3200] + bias
        gemm_bf16split<<<dim3(C_ / 128, (M_ + 127) / 128), blk, 0, stream>>>(
            xh, xl, wh, wl, proj_b, out, M_, C_);
    } else {
        // Fallback: in-kernel conversion GEMMs (previous round's path)
        gemm_split<<<dim3(C3_ / 128, (M_ + 127) / 128), blk, 0, stream>>>(
            x, qkv_w, qkv_b, qkv, M_, C3_);
        rmsnorm_kernel<<<dim3(M_ * 2), blk, 0, stream>>>(qkv, q_norm_w, k_norm_w);
        flash_mfma<<<dim3((N_ + 63) / 64, H_, B_), blk, 0, stream>>>(qkv, attn_out);
        gemm_split<<<dim3(C_ / 128, (M_ + 127) / 128), blk, 0, stream>>>(
            attn_out, proj_w, proj_b, out, M_, C_);
    }
}